// Round 8
// baseline (52.410 us; speedup 1.0000x reference)
//
#include <hip/hip_runtime.h>
#include <stdint.h>
#include <math.h>

#define NBOX 18
#define BB 512
#define DD 2048
#define NOBJ 16
#define KK 3
#define NCLS 174
#define NCAT 321
#define NSL 16           /* col-slices per b */
#define SCAND 512        /* candidates per slice block */
#define NPART 64         /* per-wave partials per b: 16 blocks x 4 waves */

// ---------------- threefry2x32 (JAX-exact, 20 rounds) ----------------
__host__ __device__ __forceinline__ uint32_t rotl32(uint32_t x, int d) {
  return (x << d) | (x >> (32 - d));
}

__host__ __device__ __forceinline__ void threefry2x32(uint32_t k0, uint32_t k1,
                                                      uint32_t x0, uint32_t x1,
                                                      uint32_t& o0, uint32_t& o1) {
  uint32_t ks2 = k0 ^ k1 ^ 0x1BD11BDAu;
  x0 += k0; x1 += k1;
#define TFR(r) x0 += x1; x1 = rotl32(x1, r); x1 ^= x0;
#define R4A TFR(13) TFR(15) TFR(26) TFR(6)
#define R4B TFR(17) TFR(29) TFR(16) TFR(24)
  R4A x0 += k1;  x1 += ks2 + 1u;
  R4B x0 += ks2; x1 += k0 + 2u;
  R4A x0 += k0;  x1 += k1 + 3u;
  R4B x0 += k1;  x1 += ks2 + 4u;
  R4A x0 += ks2; x1 += k0 + 5u;
#undef R4A
#undef R4B
#undef TFR
  o0 = x0; o1 = x1;
}

__device__ __forceinline__ float bits_to_unit(uint32_t bits) {
  float f = __uint_as_float((bits >> 9) | 0x3f800000u);
  return f - 1.0f;
}

// async global->LDS, 16B per lane, no VGPR round-trip
__device__ __forceinline__ void gload_lds16(const void* g, void* l) {
  __builtin_amdgcn_global_load_lds(
      (const __attribute__((address_space(1))) unsigned int*)g,
      (__attribute__((address_space(3))) unsigned int*)l, 16, 0, 0);
}

// ---- K1: sampler slice + async-LDS ori/mean16 stream ----
// grid 8192 = (b, slice o); 256 threads = 4 waves.
__global__ __launch_bounds__(256) void sample_stream_kernel(
    const float* __restrict__ obj_fea, const float* __restrict__ cooc,
    const int* __restrict__ obj_cat, const int* __restrict__ labels,
    uint32_t r1h, uint32_t r1l,
    unsigned long long* __restrict__ part, int* __restrict__ cnts,
    float* __restrict__ ori, float4* __restrict__ m16ws) {
  const int gb = blockIdx.x;
  const int b = gb >> 4;
  const int o = gb & 15;
  const int tid = threadIdx.x;
  const int lane = tid & 63;
  const int wid = tid >> 6;

  __shared__ float4 slds[NBOX * 32];     // 9 KB: [18 rows][32 float4 cols]
  __shared__ unsigned short jl[SCAND];   // 1 KB, per-wave 128-stripes
  __shared__ float wl[SCAND];            // 2 KB

  // ---- p0: issue the async stream (9 wave-loads; load i covers rows 2i,2i+1)
  const int col0 = o << 5;  // float4 col base of this slice
  const float4* fea4 = (const float4*)obj_fea;
  {
    const float4* gbase = fea4 + (size_t)b * NBOX * 512 + col0;
    for (int i = wid; i < 9; i += 4) {
      const float4* g = gbase + (size_t)(2 * i + (lane >> 5)) * 512 + (lane & 31);
      gload_lds16((const void*)g, (void*)((char*)slds + i * 1024));
    }
  }
  __builtin_amdgcn_sched_barrier(0);  // pin the async issue above everything

  // ---- p1: per-wave ordered compaction (ballot+popcount; j-ascending)
  const int lab = labels[b];
  const float* crow = cooc + (size_t)lab * NCAT;
  const int seg = wid << 7;               // LDS stripe base (128)
  const int jbase = (o << 9) + seg;       // candidate stripe base
  int cnt = 0;
#pragma unroll 1
  for (int c = 0; c < 2; ++c) {
    int j = jbase + (c << 6) + lane;
    int jb = j >> 4;
    float w = 0.0f;
    if (jb != b) w = crow[obj_cat[jb * NBOX + 2 + (j & 15)]];
    unsigned long long m = __ballot(w > 0.0f);
    if (w > 0.0f) {
      int rank = __popcll(m & ((1ull << lane) - 1ull));
      jl[seg + cnt + rank] = (unsigned short)j;
      wl[seg + cnt + rank] = w;
    }
    cnt += __popcll(m);
  }

  // ---- p2: 3-in-1 exponential races: argmax(g+log w) == argmax(w/-log2 u)
  const uint32_t cbase0 = ((uint32_t)b) << 13;  // k stride = 1<<22
  const uint32_t kstep = 1u << 22;
  float bw0 = 0.f, bt0 = 1.f, bw1 = 0.f, bt1 = 1.f, bw2 = 0.f, bt2 = 1.f;
  int bj0 = 0, bj1 = 0, bj2 = 0;
#pragma unroll 1
  for (int p = lane; p < cnt; p += 64) {
    uint32_t j = jl[seg + p];
    float w = wl[seg + p];
    uint32_t cc = cbase0 + j;
    uint32_t x0, x1, y0, y1, z0, z1;
    threefry2x32(r1h, r1l, 0u, cc, x0, x1);
    threefry2x32(r1h, r1l, 0u, cc + kstep, y0, y1);
    threefry2x32(r1h, r1l, 0u, cc + 2u * kstep, z0, z1);
    float t0 = -__log2f(fmaxf(bits_to_unit(x0 ^ x1), 1.1920929e-07f));
    float t1 = -__log2f(fmaxf(bits_to_unit(y0 ^ y1), 1.1920929e-07f));
    float t2 = -__log2f(fmaxf(bits_to_unit(z0 ^ z1), 1.1920929e-07f));
    if (w * bt0 > bw0 * t0) { bw0 = w; bt0 = t0; bj0 = (int)j; }  // strict >
    if (w * bt1 > bw1 * t1) { bw1 = w; bt1 = t1; bj1 = (int)j; }
    if (w * bt2 > bw2 * t2) { bw2 = w; bt2 = t2; bj2 = (int)j; }
  }
#pragma unroll
  for (int mm = 1; mm < 64; mm <<= 1) {
    float ow, ot; int oj;
    ow = __shfl_xor(bw0, mm, 64); ot = __shfl_xor(bt0, mm, 64); oj = __shfl_xor(bj0, mm, 64);
    { float lv = ow * bt0, rv = bw0 * ot;
      if (lv > rv || (lv == rv && oj < bj0)) { bw0 = ow; bt0 = ot; bj0 = oj; } }
    ow = __shfl_xor(bw1, mm, 64); ot = __shfl_xor(bt1, mm, 64); oj = __shfl_xor(bj1, mm, 64);
    { float lv = ow * bt1, rv = bw1 * ot;
      if (lv > rv || (lv == rv && oj < bj1)) { bw1 = ow; bt1 = ot; bj1 = oj; } }
    ow = __shfl_xor(bw2, mm, 64); ot = __shfl_xor(bt2, mm, 64); oj = __shfl_xor(bj2, mm, 64);
    { float lv = ow * bt2, rv = bw2 * ot;
      if (lv > rv || (lv == rv && oj < bj2)) { bw2 = ow; bt2 = ot; bj2 = oj; } }
  }
  if (lane == 0) {
    const int pw = (o << 2) + wid;
    const size_t pb = (size_t)b * KK * NPART;
    part[pb + 0 * NPART + pw] =
        ((unsigned long long)__float_as_uint(bw0 / bt0) << 32) | (uint32_t)(8192 - bj0);
    part[pb + 1 * NPART + pw] =
        ((unsigned long long)__float_as_uint(bw1 / bt1) << 32) | (uint32_t)(8192 - bj1);
    part[pb + 2 * NPART + pw] =
        ((unsigned long long)__float_as_uint(bw2 / bt2) << 32) | (uint32_t)(8192 - bj2);
    cnts[b * NPART + pw] = cnt;
  }

  // ---- p3: barrier drains the async stream; wave 0 reduces the tile
  __syncthreads();
  if (wid == 0) {
    const int col = lane & 31;
    const int rh = lane >> 5;  // 0: rows 0..8, 1: rows 9..17
    float4 acc = make_float4(0.f, 0.f, 0.f, 0.f);
    float4 v0 = acc, v1 = acc;
#pragma unroll
    for (int r = 0; r < 9; ++r) {
      float4 t = slds[(rh * 9 + r) * 32 + col];
      if (r == 0) v0 = t;
      if (r == 1) v1 = t;
      acc.x += t.x; acc.y += t.y; acc.z += t.z; acc.w += t.w;
    }
    float4 oth;
    oth.x = __shfl_xor(acc.x, 32, 64); oth.y = __shfl_xor(acc.y, 32, 64);
    oth.z = __shfl_xor(acc.z, 32, 64); oth.w = __shfl_xor(acc.w, 32, 64);
    if (rh == 0) {
      float4 S = make_float4(acc.x + oth.x, acc.y + oth.y, acc.z + oth.z, acc.w + oth.w);
      const float i18 = 1.0f / 18.0f, i16 = 1.0f / 16.0f;
      const size_t oidx = (size_t)b * 512 + col0 + col;
      ((float4*)ori)[oidx] = make_float4(S.x * i18, S.y * i18, S.z * i18, S.w * i18);
      m16ws[oidx] = make_float4((S.x - v0.x - v1.x) * i16, (S.y - v0.y - v1.y) * i16,
                                (S.z - v0.z - v1.z) * i16, (S.w - v0.w - v1.w) * i16);
    }
  }
}

// ---- K2: meta combine + mix_fea + mix_label ----
__global__ __launch_bounds__(256) void mix_kernel(
    const float* __restrict__ obj_fea, const int* __restrict__ obj_ind,
    const int* __restrict__ labels,
    const unsigned long long* __restrict__ part, const int* __restrict__ cnts,
    const float4* __restrict__ m16ws,
    uint32_t r2h, uint32_t r2l, uint32_t r3bh, uint32_t r3bl,
    float* __restrict__ mixf, float* __restrict__ mixl) {
  const int bx = blockIdx.x;
  const int b = bx >> 1;
  const int h = bx & 1;
  const int tid = threadIdx.x;
  const int off = (h << 8) + tid;

  __shared__ int s_sel[KK];
  __shared__ int s_slots[KK];
  __shared__ float s_lam;
  __shared__ int s_cnt;
  __shared__ int s_any;

  if (tid < 64) {  // wave 0: parallel 64-partial max-combine per k + cnt-or
    unsigned long long p0 = part[((size_t)b * KK + 0) * NPART + tid];
    unsigned long long p1 = part[((size_t)b * KK + 1) * NPART + tid];
    unsigned long long p2 = part[((size_t)b * KK + 2) * NPART + tid];
    int ct = cnts[b * NPART + tid];
#pragma unroll
    for (int mm = 1; mm < 64; mm <<= 1) {
      unsigned long long q;
      q = __shfl_xor(p0, mm, 64); if (q > p0) p0 = q;
      q = __shfl_xor(p1, mm, 64); if (q > p1) p1 = q;
      q = __shfl_xor(p2, mm, 64); if (q > p2) p2 = q;
      ct |= __shfl_xor(ct, mm, 64);
    }
    if (tid == 0) {
      s_sel[0] = 8192 - (int)(p0 & 0xFFFFFFFFull);
      s_sel[1] = 8192 - (int)(p1 & 0xFFFFFFFFull);
      s_sel[2] = 8192 - (int)(p2 & 0xFFFFFFFFull);
      s_cnt = ct;
    }
  } else if (tid < 67) {  // slots (randint lower-bits under split subkey k2)
    const int k = tid - 64;
    uint32_t s0, s1;
    threefry2x32(r3bh, r3bl, 0u, (uint32_t)(b * KK + k), s0, s1);
    s_slots[k] = (int)((s0 ^ s1) & 15u);
  } else if (tid == 67) {
    uint32_t c0, c1;
    threefry2x32(r2h, r2l, 0u, (uint32_t)b, c0, c1);
    s_lam = bits_to_unit(c0 ^ c1);
  } else if (tid == 68) {
    int any = 0;
#pragma unroll
    for (int oo = 0; oo < NOBJ; ++oo) any |= (obj_ind[b * NBOX + 2 + oo] != 0);
    s_any = any;
  }
  __syncthreads();

  const int hc = (s_cnt != 0) && s_any;
  const float l = s_lam, l1 = 1.0f - l;
  const float4* fea4 = (const float4*)obj_fea;
  float4* mixf4 = (float4*)mixf;
  if (hc) {
#pragma unroll 1
    for (int k = 0; k < KK; ++k) {
      int s = s_sel[k];
      int bi = s >> 4, bo = s & 15, sl = s_slots[k];
      float4 a = fea4[((size_t)b * NBOX + 2 + sl) * 512 + off];
      float4 e = fea4[((size_t)bi * NBOX + 2 + bo) * 512 + off];
      float4 ov;
      ov.x = a.x * l + e.x * l1; ov.y = a.y * l + e.y * l1;
      ov.z = a.z * l + e.z * l1; ov.w = a.w * l + e.w * l1;
      mixf4[((size_t)b * KK + k) * 512 + off] = ov;
    }
  } else {
    float4 m16 = m16ws[(size_t)b * 512 + off];
#pragma unroll
    for (int k = 0; k < KK; ++k) mixf4[((size_t)b * KK + k) * 512 + off] = m16;
  }

  if (h == 0 && tid < NCLS) {
    int lb = labels[b];
#pragma unroll 1
    for (int k = 0; k < KK; ++k) {
      float val;
      if (hc) {
        int ls = labels[s_sel[k] >> 4];
        val = (tid == lb ? l : 0.0f) + (tid == ls ? l1 : 0.0f);
      } else {
        val = (tid == lb) ? 1.0f : 0.0f;
      }
      mixl[(size_t)(b * KK + k) * NCLS + tid] = val;
    }
  }
}

extern "C" void kernel_launch(void* const* d_in, const int* in_sizes, int n_in,
                              void* d_out, int out_size, void* d_ws, size_t ws_size,
                              hipStream_t stream) {
  (void)in_sizes; (void)n_in; (void)out_size; (void)ws_size;
  const float* obj_fea = (const float*)d_in[0];
  const float* cooc    = (const float*)d_in[1];
  const int* obj_ind   = (const int*)d_in[2];
  const int* obj_cat   = (const int*)d_in[3];
  const int* labels    = (const int*)d_in[4];

  float* out  = (float*)d_out;
  float* ori  = out;                              // 512*2048
  float* mixf = out + (size_t)BB * DD;            // 512*3*2048
  float* mixl = mixf + (size_t)BB * KK * DD;      // 512*3*174

  char* ws = (char*)d_ws;
  unsigned long long* part = (unsigned long long*)ws;        // 512*3*64*8 = 768 KB
  int* cnts = (int*)(ws + (size_t)BB * KK * NPART * 8);      // 512*64*4  = 128 KB
  float4* m16ws = (float4*)(ws + 1024 * 1024);               // 4 MB

  // key(42) -> split 3 (partitionable/fold-like): r_i = threefry(key,(0,i))
  uint32_t r1h, r1l, r2h, r2l, r3h, r3l;
  threefry2x32(0u, 42u, 0u, 0u, r1h, r1l);
  threefry2x32(0u, 42u, 0u, 1u, r2h, r2l);
  threefry2x32(0u, 42u, 0u, 2u, r3h, r3l);
  // randint(r3,...) splits internally: k1,k2 = split(r3); lower_bits uses k2
  uint32_t r3bh, r3bl;
  threefry2x32(r3h, r3l, 0u, 1u, r3bh, r3bl);

  hipLaunchKernelGGL(sample_stream_kernel, dim3(BB * NSL), dim3(256), 0, stream,
                     obj_fea, cooc, obj_cat, labels, r1h, r1l,
                     part, cnts, ori, m16ws);
  hipLaunchKernelGGL(mix_kernel, dim3(BB * 2), dim3(256), 0, stream,
                     obj_fea, obj_ind, labels, part, cnts, m16ws,
                     r2h, r2l, r3bh, r3bl, mixf, mixl);
}

// Round 9
// 48.495 us; speedup vs baseline: 1.0807x; 1.0807x over previous
//
#include <hip/hip_runtime.h>
#include <stdint.h>
#include <math.h>

#define NBOX 18
#define BB 512
#define DD 2048
#define NOBJ 16
#define KK 3
#define NCLS 174
#define NCAT 321
#define NQ 4
#define QCAND 2048
#define NPART 16  /* per-wave partials per b: 4 blocks x 4 waves */

// ---------------- threefry2x32 (JAX-exact, 20 rounds) ----------------
__host__ __device__ __forceinline__ uint32_t rotl32(uint32_t x, int d) {
  return (x << d) | (x >> (32 - d));
}

__host__ __device__ __forceinline__ void threefry2x32(uint32_t k0, uint32_t k1,
                                                      uint32_t x0, uint32_t x1,
                                                      uint32_t& o0, uint32_t& o1) {
  uint32_t ks2 = k0 ^ k1 ^ 0x1BD11BDAu;
  x0 += k0; x1 += k1;
#define TFR(r) x0 += x1; x1 = rotl32(x1, r); x1 ^= x0;
#define R4A TFR(13) TFR(15) TFR(26) TFR(6)
#define R4B TFR(17) TFR(29) TFR(16) TFR(24)
  R4A x0 += k1;  x1 += ks2 + 1u;
  R4B x0 += ks2; x1 += k0 + 2u;
  R4A x0 += k0;  x1 += k1 + 3u;
  R4B x0 += k1;  x1 += ks2 + 4u;
  R4A x0 += ks2; x1 += k0 + 5u;
#undef R4A
#undef R4B
#undef TFR
  o0 = x0; o1 = x1;
}

__device__ __forceinline__ float bits_to_unit(uint32_t bits) {
  float f = __uint_as_float((bits >> 9) | 0x3f800000u);
  return f - 1.0f;
}

// async global->LDS, 16B per lane (lds dest = wave-uniform base + lane*16)
__device__ __forceinline__ void gload_lds16(const void* g, void* l) {
  __builtin_amdgcn_global_load_lds(
      (const __attribute__((address_space(1))) unsigned int*)g,
      (__attribute__((address_space(3))) unsigned int*)l, 16, 0, 0);
}

// ---- K1: sampler quarter + async-LDS ori/mean16 stream ----
// grid 2048 = (b, quarter q); 256 threads = 4 waves; LDS 48.2 KB -> 3 blocks/CU.
__global__ __launch_bounds__(256) void sample_stream_kernel(
    const float* __restrict__ obj_fea, const float* __restrict__ cooc,
    const int* __restrict__ obj_cat, const int* __restrict__ labels,
    uint32_t r1h, uint32_t r1l,
    unsigned long long* __restrict__ part, int* __restrict__ cnts,
    float* __restrict__ ori, float4* __restrict__ m16ws) {
  const int gb = blockIdx.x;
  const int b = gb >> 2;
  const int q = gb & 3;
  const int tid = threadIdx.x;
  const int lane = tid & 63;
  const int wid = tid >> 6;

  __shared__ float4 slds[NBOX * 128];   // 36 KB: [18 rows][128 float4 cols]
  __shared__ unsigned short jl[QCAND];  // 4 KB, per-wave 512-stripes
  __shared__ float wl[QCAND];           // 8 KB

  // ---- p0: issue the async stream at t=0 (36 x 1KB wave-loads, 9 per wave)
  const int col0 = q << 7;  // float4 col base of this quarter
  const float4* fea4 = (const float4*)obj_fea;
  const float4* gbase = fea4 + (size_t)b * NBOX * 512 + col0;
#pragma unroll
  for (int i = 0; i < 9; ++i) {
    const int L = wid * 9 + i;           // 0..35: (row, half-row)
    const int r = L >> 1, hh = L & 1;
    const float4* g = gbase + (size_t)r * 512 + hh * 64 + lane;
    gload_lds16((const void*)g, (void*)((char*)slds + (size_t)L * 1024));
  }
  __builtin_amdgcn_sched_barrier(0);  // pin the async issue above everything

  // ---- p1: per-wave ordered compaction (ballot+popcount; j-ascending)
  const int lab = labels[b];
  const float* crow = cooc + (size_t)lab * NCAT;
  const int seg = wid << 9;               // wave's LDS stripe base (512)
  const int jbase = (q << 11) + seg;      // wave's candidate stripe base
  int cnt = 0;
#pragma unroll 1
  for (int c = 0; c < 8; ++c) {
    int j = jbase + (c << 6) + lane;
    int jb = j >> 4;
    float w = 0.0f;
    if (jb != b) w = crow[obj_cat[jb * NBOX + 2 + (j & 15)]];
    unsigned long long m = __ballot(w > 0.0f);
    if (w > 0.0f) {
      int rank = __popcll(m & ((1ull << lane) - 1ull));
      jl[seg + cnt + rank] = (unsigned short)j;
      wl[seg + cnt + rank] = w;
    }
    cnt += __popcll(m);
  }

  // ---- p2: 3-in-1 exponential races: argmax(g+log w) == argmax(w/-log2 u)
  const uint32_t cbase0 = ((uint32_t)b) << 13;  // k stride = 1<<22
  const uint32_t kstep = 1u << 22;
  float bw0 = 0.f, bt0 = 1.f, bw1 = 0.f, bt1 = 1.f, bw2 = 0.f, bt2 = 1.f;
  int bj0 = 0, bj1 = 0, bj2 = 0;
#pragma unroll 1
  for (int p = lane; p < cnt; p += 64) {
    uint32_t j = jl[seg + p];
    float w = wl[seg + p];
    uint32_t cc = cbase0 + j;
    uint32_t x0, x1, y0, y1, z0, z1;
    threefry2x32(r1h, r1l, 0u, cc, x0, x1);
    threefry2x32(r1h, r1l, 0u, cc + kstep, y0, y1);
    threefry2x32(r1h, r1l, 0u, cc + 2u * kstep, z0, z1);
    float t0 = -__log2f(fmaxf(bits_to_unit(x0 ^ x1), 1.1920929e-07f));
    float t1 = -__log2f(fmaxf(bits_to_unit(y0 ^ y1), 1.1920929e-07f));
    float t2 = -__log2f(fmaxf(bits_to_unit(z0 ^ z1), 1.1920929e-07f));
    if (w * bt0 > bw0 * t0) { bw0 = w; bt0 = t0; bj0 = (int)j; }  // strict >
    if (w * bt1 > bw1 * t1) { bw1 = w; bt1 = t1; bj1 = (int)j; }
    if (w * bt2 > bw2 * t2) { bw2 = w; bt2 = t2; bj2 = (int)j; }
  }
#pragma unroll
  for (int mm = 1; mm < 64; mm <<= 1) {
    float ow, ot; int oj;
    ow = __shfl_xor(bw0, mm, 64); ot = __shfl_xor(bt0, mm, 64); oj = __shfl_xor(bj0, mm, 64);
    { float lv = ow * bt0, rv = bw0 * ot;
      if (lv > rv || (lv == rv && oj < bj0)) { bw0 = ow; bt0 = ot; bj0 = oj; } }
    ow = __shfl_xor(bw1, mm, 64); ot = __shfl_xor(bt1, mm, 64); oj = __shfl_xor(bj1, mm, 64);
    { float lv = ow * bt1, rv = bw1 * ot;
      if (lv > rv || (lv == rv && oj < bj1)) { bw1 = ow; bt1 = ot; bj1 = oj; } }
    ow = __shfl_xor(bw2, mm, 64); ot = __shfl_xor(bt2, mm, 64); oj = __shfl_xor(bj2, mm, 64);
    { float lv = ow * bt2, rv = bw2 * ot;
      if (lv > rv || (lv == rv && oj < bj2)) { bw2 = ow; bt2 = ot; bj2 = oj; } }
  }
  if (lane == 0) {
    const int pw = (q << 2) + wid;
    const size_t pb = (size_t)b * KK * NPART;
    part[pb + 0 * NPART + pw] =
        ((unsigned long long)__float_as_uint(bw0 / bt0) << 32) | (uint32_t)(8192 - bj0);
    part[pb + 1 * NPART + pw] =
        ((unsigned long long)__float_as_uint(bw1 / bt1) << 32) | (uint32_t)(8192 - bj1);
    part[pb + 2 * NPART + pw] =
        ((unsigned long long)__float_as_uint(bw2 / bt2) << 32) | (uint32_t)(8192 - bj2);
    cnts[b * NPART + pw] = cnt;
  }

  // ---- p3: barrier drains the async stream; lane-pair reduce of the tile
  __syncthreads();
  const int rh = tid & 1;        // 0: rows 0..8, 1: rows 9..17
  const int col = tid >> 1;      // 0..127
  float4 acc = make_float4(0.f, 0.f, 0.f, 0.f);
#pragma unroll
  for (int r = 0; r < 9; ++r) {
    float4 t = slds[(rh * 9 + r) * 128 + col];
    acc.x += t.x; acc.y += t.y; acc.z += t.z; acc.w += t.w;
  }
  float4 oth;
  oth.x = __shfl_xor(acc.x, 1, 64); oth.y = __shfl_xor(acc.y, 1, 64);
  oth.z = __shfl_xor(acc.z, 1, 64); oth.w = __shfl_xor(acc.w, 1, 64);
  if (rh == 0) {
    float4 S = make_float4(acc.x + oth.x, acc.y + oth.y, acc.z + oth.z, acc.w + oth.w);
    float4 v0 = slds[col];
    float4 v1 = slds[128 + col];
    const float i18 = 1.0f / 18.0f, i16 = 1.0f / 16.0f;
    const size_t oidx = (size_t)b * 512 + col0 + col;
    ((float4*)ori)[oidx] = make_float4(S.x * i18, S.y * i18, S.z * i18, S.w * i18);
    m16ws[oidx] = make_float4((S.x - v0.x - v1.x) * i16, (S.y - v0.y - v1.y) * i16,
                              (S.z - v0.z - v1.z) * i16, (S.w - v0.w - v1.w) * i16);
  }
}

// ---- K2: meta combine + mix_fea + mix_label ----
__global__ __launch_bounds__(256) void mix_kernel(
    const float* __restrict__ obj_fea, const int* __restrict__ obj_ind,
    const int* __restrict__ labels,
    const unsigned long long* __restrict__ part, const int* __restrict__ cnts,
    const float4* __restrict__ m16ws,
    uint32_t r2h, uint32_t r2l, uint32_t r3bh, uint32_t r3bl,
    float* __restrict__ mixf, float* __restrict__ mixl) {
  const int bx = blockIdx.x;
  const int b = bx >> 1;
  const int h = bx & 1;
  const int tid = threadIdx.x;
  const int off = (h << 8) + tid;

  __shared__ int s_sel[KK];
  __shared__ int s_slots[KK];
  __shared__ float s_lam;
  __shared__ int s_cnt;
  __shared__ int s_any;

  if (tid < NPART) {  // lanes 0-15: parallel 16-partial max-combine + cnt-or
    unsigned long long p0 = part[((size_t)b * KK + 0) * NPART + tid];
    unsigned long long p1 = part[((size_t)b * KK + 1) * NPART + tid];
    unsigned long long p2 = part[((size_t)b * KK + 2) * NPART + tid];
    int ct = cnts[b * NPART + tid];
#pragma unroll
    for (int mm = 1; mm < NPART; mm <<= 1) {
      unsigned long long qq;
      qq = __shfl_xor(p0, mm, 64); if (qq > p0) p0 = qq;
      qq = __shfl_xor(p1, mm, 64); if (qq > p1) p1 = qq;
      qq = __shfl_xor(p2, mm, 64); if (qq > p2) p2 = qq;
      ct |= __shfl_xor(ct, mm, 64);
    }
    if (tid == 0) {
      s_sel[0] = 8192 - (int)(p0 & 0xFFFFFFFFull);
      s_sel[1] = 8192 - (int)(p1 & 0xFFFFFFFFull);
      s_sel[2] = 8192 - (int)(p2 & 0xFFFFFFFFull);
      s_cnt = ct;
    }
  } else if (tid < NPART + KK) {  // slots (randint lower-bits, split subkey k2)
    const int k = tid - NPART;
    uint32_t s0, s1;
    threefry2x32(r3bh, r3bl, 0u, (uint32_t)(b * KK + k), s0, s1);
    s_slots[k] = (int)((s0 ^ s1) & 15u);
  } else if (tid == NPART + KK) {
    uint32_t c0, c1;
    threefry2x32(r2h, r2l, 0u, (uint32_t)b, c0, c1);
    s_lam = bits_to_unit(c0 ^ c1);
  } else if (tid == NPART + KK + 1) {
    int any = 0;
#pragma unroll
    for (int oo = 0; oo < NOBJ; ++oo) any |= (obj_ind[b * NBOX + 2 + oo] != 0);
    s_any = any;
  }
  __syncthreads();

  const int hc = (s_cnt != 0) && s_any;
  const float l = s_lam, l1 = 1.0f - l;
  const float4* fea4 = (const float4*)obj_fea;
  float4* mixf4 = (float4*)mixf;
  if (hc) {
#pragma unroll 1
    for (int k = 0; k < KK; ++k) {
      int s = s_sel[k];
      int bi = s >> 4, bo = s & 15, sl = s_slots[k];
      float4 a = fea4[((size_t)b * NBOX + 2 + sl) * 512 + off];
      float4 e = fea4[((size_t)bi * NBOX + 2 + bo) * 512 + off];
      float4 ov;
      ov.x = a.x * l + e.x * l1; ov.y = a.y * l + e.y * l1;
      ov.z = a.z * l + e.z * l1; ov.w = a.w * l + e.w * l1;
      mixf4[((size_t)b * KK + k) * 512 + off] = ov;
    }
  } else {
    float4 m16 = m16ws[(size_t)b * 512 + off];
#pragma unroll
    for (int k = 0; k < KK; ++k) mixf4[((size_t)b * KK + k) * 512 + off] = m16;
  }

  if (h == 0 && tid < NCLS) {
    int lb = labels[b];
#pragma unroll 1
    for (int k = 0; k < KK; ++k) {
      float val;
      if (hc) {
        int ls = labels[s_sel[k] >> 4];
        val = (tid == lb ? l : 0.0f) + (tid == ls ? l1 : 0.0f);
      } else {
        val = (tid == lb) ? 1.0f : 0.0f;
      }
      mixl[(size_t)(b * KK + k) * NCLS + tid] = val;
    }
  }
}

extern "C" void kernel_launch(void* const* d_in, const int* in_sizes, int n_in,
                              void* d_out, int out_size, void* d_ws, size_t ws_size,
                              hipStream_t stream) {
  (void)in_sizes; (void)n_in; (void)out_size; (void)ws_size;
  const float* obj_fea = (const float*)d_in[0];
  const float* cooc    = (const float*)d_in[1];
  const int* obj_ind   = (const int*)d_in[2];
  const int* obj_cat   = (const int*)d_in[3];
  const int* labels    = (const int*)d_in[4];

  float* out  = (float*)d_out;
  float* ori  = out;                              // 512*2048
  float* mixf = out + (size_t)BB * DD;            // 512*3*2048
  float* mixl = mixf + (size_t)BB * KK * DD;      // 512*3*174

  char* ws = (char*)d_ws;
  unsigned long long* part = (unsigned long long*)ws;        // 512*3*16*8 = 192 KB
  int* cnts = (int*)(ws + (size_t)BB * KK * NPART * 8);      // 512*16*4  =  32 KB
  float4* m16ws = (float4*)(ws + 1024 * 1024);               // 4 MB

  // key(42) -> split 3 (partitionable/fold-like): r_i = threefry(key,(0,i))
  uint32_t r1h, r1l, r2h, r2l, r3h, r3l;
  threefry2x32(0u, 42u, 0u, 0u, r1h, r1l);
  threefry2x32(0u, 42u, 0u, 1u, r2h, r2l);
  threefry2x32(0u, 42u, 0u, 2u, r3h, r3l);
  // randint(r3,...) splits internally: k1,k2 = split(r3); lower_bits uses k2
  uint32_t r3bh, r3bl;
  threefry2x32(r3h, r3l, 0u, 1u, r3bh, r3bl);

  hipLaunchKernelGGL(sample_stream_kernel, dim3(BB * NQ), dim3(256), 0, stream,
                     obj_fea, cooc, obj_cat, labels, r1h, r1l,
                     part, cnts, ori, m16ws);
  hipLaunchKernelGGL(mix_kernel, dim3(BB * 2), dim3(256), 0, stream,
                     obj_fea, obj_ind, labels, part, cnts, m16ws,
                     r2h, r2l, r3bh, r3bl, mixf, mixl);
}